// Round 5
// baseline (137.537 us; speedup 1.0000x reference)
//
#include <hip/hip_runtime.h>

#define DEV __device__ __forceinline__

// Fixed-size value-semantics vector (pure SSA after inlining).
template <int N> struct V { float v[N == 0 ? 1 : N]; };

// General Batcher odd-even merge, by value. Identical logic to rounds 2/3
// (verified absmax = 0.0 on hardware twice).
template <int M, int N>
DEV V<M + N> mrg(V<M> a, V<N> b) {
    V<M + N> o;
    if constexpr (M == 0) {
#pragma unroll
        for (int i = 0; i < N; ++i) o.v[i] = b.v[i];
    } else if constexpr (N == 0) {
#pragma unroll
        for (int i = 0; i < M; ++i) o.v[i] = a.v[i];
    } else if constexpr (M == 1 && N == 1) {
        o.v[0] = fminf(a.v[0], b.v[0]);
        o.v[1] = fmaxf(a.v[0], b.v[0]);
    } else if constexpr ((M & 1) && (N & 1)) {
        constexpr int AE = (M + 1) / 2, AO = M / 2, BE = (N + 1) / 2, BO = N / 2;
        V<AE> ae; V<AO> ao; V<BE> be; V<BO> bo;
#pragma unroll
        for (int i = 0; i < AE; ++i) ae.v[i] = a.v[2 * i];
#pragma unroll
        for (int i = 0; i < AO; ++i) ao.v[i] = a.v[2 * i + 1];
#pragma unroll
        for (int i = 0; i < BE; ++i) be.v[i] = b.v[2 * i];
#pragma unroll
        for (int i = 0; i < BO; ++i) bo.v[i] = b.v[2 * i + 1];
        V<AE + BO> E = mrg<AE, BO>(ae, bo);
        V<AO + BE> O = mrg<AO, BE>(ao, be);
        constexpr int P = AE + BO;
#pragma unroll
        for (int i = 0; i < P; ++i) {
            o.v[2 * i] = fminf(E.v[i], O.v[i]);
            o.v[2 * i + 1] = fmaxf(E.v[i], O.v[i]);
        }
    } else {
        constexpr int AE = (M + 1) / 2, AO = M / 2, BE = (N + 1) / 2, BO = N / 2;
        V<AE> ae; V<AO> ao; V<BE> be; V<BO> bo;
#pragma unroll
        for (int i = 0; i < AE; ++i) ae.v[i] = a.v[2 * i];
#pragma unroll
        for (int i = 0; i < AO; ++i) ao.v[i] = a.v[2 * i + 1];
#pragma unroll
        for (int i = 0; i < BE; ++i) be.v[i] = b.v[2 * i];
#pragma unroll
        for (int i = 0; i < BO; ++i) bo.v[i] = b.v[2 * i + 1];
        V<AE + BE> E = mrg<AE, BE>(ae, be);
        V<AO + BO> O = mrg<AO, BO>(ao, bo);
        constexpr int CEn = AE + BE, COn = AO + BO;
        o.v[0] = E.v[0];
#pragma unroll
        for (int i = 0; i < COn; ++i) {
            if (i + 1 < CEn) {
                o.v[2 * i + 1] = fminf(O.v[i], E.v[i + 1]);
                o.v[2 * i + 2] = fmaxf(O.v[i], E.v[i + 1]);
            } else {
                o.v[2 * i + 1] = O.v[i];
            }
        }
    }
    return o;
}

DEV void ce(float& a, float& b) {
    float lo = fminf(a, b);
    b = fmaxf(a, b);
    a = lo;
}

// sort7 = sort3 (min3/med3/max3, 3 instrs) + sort4 (5 CE) + merge(3,4).
DEV V<7> sort7(V<7> x) {
    float a = x.v[0], b = x.v[1], c = x.v[2];
    V<3> s3;
    s3.v[0] = fminf(fminf(a, b), c);              // -> v_min3_f32
    s3.v[1] = __builtin_amdgcn_fmed3f(a, b, c);   // exact median (no NaN here)
    s3.v[2] = fmaxf(fmaxf(a, b), c);              // -> v_max3_f32
    ce(x.v[3], x.v[4]); ce(x.v[5], x.v[6]);
    ce(x.v[3], x.v[5]); ce(x.v[4], x.v[6]); ce(x.v[4], x.v[5]);
    V<4> s4;
    s4.v[0] = x.v[3]; s4.v[1] = x.v[4]; s4.v[2] = x.v[5]; s4.v[3] = x.v[6];
    return mrg<3, 4>(s3, s4);
}

// rank-24 (0-indexed) of union(Q[0..27], F[0..20]):
// min over i+j==25 of max(Q[i-1], F[j-1]); tree-reduced (verified identity).
DEV float sel24(const V<28>& Q, const V<21>& F) {
    float t[22];
    t[21] = Q.v[24];  // i = 25, j = 0
#pragma unroll
    for (int i = 4; i < 25; ++i) t[i - 4] = fmaxf(Q.v[i - 1], F.v[24 - i]);
#pragma unroll
    for (int i = 0; i < 11; ++i) t[i] = fminf(t[i], t[i + 11]);
#pragma unroll
    for (int i = 0; i < 5; ++i) t[i] = fminf(t[i], t[i + 6]);
#pragma unroll
    for (int i = 0; i < 3; ++i) t[i] = fminf(t[i], t[i + 3]);
    return fminf(fminf(t[0], t[1]), t[2]);
}

static constexpr int W = 512, H = 512, PLANE = W * H;

// One block = one image row (y block-uniform -> row bases scalarize to SGPR).
// Each thread: 4 consecutive pixels. Same decomposition as round 3 (verified):
//   Q = merge(c3..c6) shared by all 4; P12=merge(c1,c2); P78=merge(c7,c8)
//   px0 = sel24(Q, mrg(P12,c0))  px1 = sel24(Q, mrg(P12,c7))
//   px2 = sel24(Q, mrg(P78,c2))  px3 = sel24(Q, mrg(P78,c9))
// Phased with sched_barrier(0) so the peak live set stays ~90 floats
// (fits arch VGPRs -> no AGPR shuttling).
__global__ __launch_bounds__(128, 1) void median7_hardtanh_kernel(
    const float* __restrict__ in, float* __restrict__ out) {
    int r = blockIdx.x;           // plane*512 + y
    int y = r & (H - 1);
    int p = r >> 9;
    const float* img = in + (size_t)p * PLANE;
    int x0 = (int)threadIdx.x << 2;

    int rows[7];  // block-uniform
#pragma unroll
    for (int i = 0; i < 7; ++i) {
        int t = y + i - 3;
        t = (t < 0) ? -t : t;
        t = (t > H - 1) ? 2 * (H - 1) - t : t;
        rows[i] = t << 9;
    }

    // reflected side-column indices (branch-free; identity for interior)
    int cl0 = x0 - 3; cl0 = cl0 < 0 ? -cl0 : cl0;
    int cl1 = x0 - 2; cl1 = cl1 < 0 ? -cl1 : cl1;
    int cl2 = x0 - 1; cl2 = cl2 < 0 ? -cl2 : cl2;
    int cr0 = x0 + 4; cr0 = cr0 > W - 1 ? 2 * (W - 1) - cr0 : cr0;
    int cr1 = x0 + 5; cr1 = cr1 > W - 1 ? 2 * (W - 1) - cr1 : cr1;
    int cr2 = x0 + 6; cr2 = cr2 > W - 1 ? 2 * (W - 1) - cr2 : cr2;

    // ---- Phase A: center columns c3..c6 via aligned float4; Q = 28-merge
    V<7> c3, c4, c5, c6;
#pragma unroll
    for (int i = 0; i < 7; ++i) {
        float4 C = *reinterpret_cast<const float4*>(img + rows[i] + x0);
        c3.v[i] = C.x; c4.v[i] = C.y; c5.v[i] = C.z; c6.v[i] = C.w;
    }
    c3 = sort7(c3); c4 = sort7(c4); c5 = sort7(c5); c6 = sort7(c6);
    V<28> Q = mrg<14, 14>(mrg<7, 7>(c3, c4), mrg<7, 7>(c5, c6));
    __builtin_amdgcn_sched_barrier(0);

    // ---- Phase B: c1, c2 (keep c2 for px2); P12
    V<7> c1, c2;
#pragma unroll
    for (int i = 0; i < 7; ++i) {
        const float* rp = img + rows[i];
        c1.v[i] = rp[cl1];
        c2.v[i] = rp[cl2];
    }
    c1 = sort7(c1); c2 = sort7(c2);
    V<14> P12 = mrg<7, 7>(c1, c2);
    __builtin_amdgcn_sched_barrier(0);

    // ---- Phase C: c0 -> px0
    V<7> c0;
#pragma unroll
    for (int i = 0; i < 7; ++i) c0.v[i] = img[rows[i] + cl0];
    c0 = sort7(c0);
    float m0 = sel24(Q, mrg<14, 7>(P12, c0));
    __builtin_amdgcn_sched_barrier(0);

    // ---- Phase D: c7 (keep) -> px1
    V<7> c7;
#pragma unroll
    for (int i = 0; i < 7; ++i) c7.v[i] = img[rows[i] + cr0];
    c7 = sort7(c7);
    float m1 = sel24(Q, mrg<14, 7>(P12, c7));
    __builtin_amdgcn_sched_barrier(0);

    // ---- Phase E/F: c8; P78; px2 (uses kept c2)
    V<7> c8;
#pragma unroll
    for (int i = 0; i < 7; ++i) c8.v[i] = img[rows[i] + cr1];
    c8 = sort7(c8);
    V<14> P78 = mrg<7, 7>(c7, c8);
    float m2 = sel24(Q, mrg<14, 7>(P78, c2));
    __builtin_amdgcn_sched_barrier(0);

    // ---- Phase G: c9 -> px3
    V<7> c9;
#pragma unroll
    for (int i = 0; i < 7; ++i) c9.v[i] = img[rows[i] + cr2];
    c9 = sort7(c9);
    float m3 = sel24(Q, mrg<14, 7>(P78, c9));

    float4 o;
    o.x = fminf(fmaxf(m0, 0.0f), 1.0f);
    o.y = fminf(fmaxf(m1, 0.0f), 1.0f);
    o.z = fminf(fmaxf(m2, 0.0f), 1.0f);
    o.w = fminf(fmaxf(m3, 0.0f), 1.0f);
    *reinterpret_cast<float4*>(out + (size_t)r * W + x0) = o;
}

extern "C" void kernel_launch(void* const* d_in, const int* in_sizes, int n_in,
                              void* d_out, int out_size, void* d_ws, size_t ws_size,
                              hipStream_t stream) {
    const float* x = (const float*)d_in[0];
    float* outp = (float*)d_out;
    int rows_total = out_size / W;  // 12288
    median7_hardtanh_kernel<<<rows_total, 128, 0, stream>>>(x, outp);
}